// Round 3
// baseline (346.761 us; speedup 1.0000x reference)
//
#include <hip/hip_runtime.h>

typedef __attribute__((ext_vector_type(8))) short short8;   // 8 bf16 = 4 VGPRs
typedef __attribute__((ext_vector_type(4))) float floatx4;  // MFMA accumulator

#define N_PTS 8192
#define D_DIM 256
#define N_PLANES 128
#define NTILE 64  // 8192 / 128

// round-to-nearest-even float -> bf16 bits
__device__ inline unsigned short f2bf(float f) {
    unsigned int x = __float_as_uint(f);
    unsigned int r = (x + 0x7fffu + ((x >> 16) & 1u)) >> 16;
    return (unsigned short)r;
}

// count of zero bytes in w (exact per-byte SWAR, no cross-byte carry)
__device__ inline int zbytes(unsigned int w) {
    unsigned int t = ((w & 0x7f7f7f7fu) + 0x7f7f7f7fu) | w | 0x7f7f7f7fu;
    return __popc(~t);  // ~t has only bit7 per byte set, iff byte == 0
}

// async global->LDS, 16B per lane; LDS dest must be base + lane*16 (m104/m108)
__device__ inline void load_lds16(const unsigned short* g, unsigned short* l) {
    __builtin_amdgcn_global_load_lds(
        (const __attribute__((address_space(1))) unsigned int*)g,
        (__attribute__((address_space(3))) unsigned int*)l, 16, 0, 0);
}

// ---------------------------------------------------------------------------
// Kernel 1: row-normalize Z (fp32) -> Zn (bf16). One wave per row.
// ---------------------------------------------------------------------------
__global__ void norm_kernel(const float* __restrict__ Z,
                            unsigned short* __restrict__ Zn) {
    int n = blockIdx.x;
    int lane = threadIdx.x;  // 0..63
    const float4* zr = (const float4*)(Z + (size_t)n * D_DIM);
    float4 v = zr[lane];  // 64 lanes x 4 floats = 256
    float ss = v.x * v.x + v.y * v.y + v.z * v.z + v.w * v.w;
#pragma unroll
    for (int off = 32; off > 0; off >>= 1) ss += __shfl_down(ss, off);
    ss = __shfl(ss, 0);
    float inv = rsqrtf(ss);
    ushort4 o;
    o.x = f2bf(v.x * inv);
    o.y = f2bf(v.y * inv);
    o.z = f2bf(v.z * inv);
    o.w = f2bf(v.w * inv);
    ((ushort4*)(Zn + (size_t)n * D_DIM))[lane] = o;
}

// ---------------------------------------------------------------------------
// Kernel 2: LSH keys. Block = 256 threads = 128 planes x 2 point-halves,
// 32 points per block. Points staged in LDS (broadcast reads); each thread
// reads its plane row ONCE (16B/step, register-cached across its 16 points).
// keys4[n][w]: word w = ballot bits of planes 32w..32w+31; byte b of the
// 16-byte key equals the reference band-b signature (same 2^r weighting).
// ---------------------------------------------------------------------------
__global__ __launch_bounds__(256) void keys_kernel(
    const float* __restrict__ Z, const float* __restrict__ planes,
    unsigned int* __restrict__ keys4) {
    __shared__ __align__(16) float zs[32][D_DIM];  // 32 KB
    int t = threadIdx.x;
    int base = blockIdx.x * 32;

    const float4* zsrc = (const float4*)(Z + (size_t)base * D_DIM);
    float4* zdst = (float4*)&zs[0][0];
#pragma unroll
    for (int i = 0; i < 8; ++i) zdst[t + i * 256] = zsrc[t + i * 256];
    __syncthreads();

    int p = t & 127;   // plane index
    int hf = t >> 7;   // 0/1 -> points 0..15 / 16..31
    int wave = t >> 6, lane = t & 63;
    const float4* pr = (const float4*)(planes + (size_t)p * D_DIM);

    float acc[16] = {};
    for (int kk = 0; kk < D_DIM / 4; ++kk) {
        float4 pv = pr[kk];
#pragma unroll
        for (int j = 0; j < 16; ++j) {
            float4 zv = *(const float4*)&zs[hf * 16 + j][kk * 4];
            acc[j] += pv.x * zv.x + pv.y * zv.y + pv.z * zv.z + pv.w * zv.w;
        }
    }

#pragma unroll
    for (int j = 0; j < 16; ++j) {
        unsigned long long mask = __ballot(acc[j] >= 0.0f);
        if (lane < 2) {
            keys4[(size_t)(base + hf * 16 + j) * 4 + (wave & 1) * 2 + lane] =
                (unsigned int)(mask >> (32 * lane));
        }
    }
}

// ---------------------------------------------------------------------------
// Kernel 3: sim GEMM (bf16 MFMA) + LSH-count epilogue, SYMMETRIC grid.
// Only upper-triangular 128x128 blocks (bi<=bj): 2080 blocks vs 4096.
// Off-diagonal blocks write their tile AND the transposed mirror tile
// (transpose staged per-wave through the dead As/Bs LDS, stores coalesced).
// K staged in 4 chunks of BK=64 via global_load_lds (16B), chunk-major LDS.
// ---------------------------------------------------------------------------
__global__ __launch_bounds__(256) void gemm_kernel(
    const unsigned short* __restrict__ Zn, const uint4* __restrict__ keys,
    float* __restrict__ out) {
    __shared__ __align__(16) unsigned short As[1024 * 8];  // 16 KB staging
    __shared__ __align__(16) unsigned short Bs[1024 * 8];  // 16 KB staging
    __shared__ uint4 krow[128];
    __shared__ uint4 kcol[128];

    // triangular decode: bi = largest b with S(b)=b*64-b*(b-1)/2 <= idx
    int idx = blockIdx.x;
    int bi = (int)((129.0f - sqrtf(16641.0f - 8.0f * (float)idx)) * 0.5f);
    while ((bi + 1) * NTILE - ((bi + 1) * bi) / 2 <= idx) ++bi;
    while (bi * NTILE - (bi * (bi - 1)) / 2 > idx) --bi;
    int bj = bi + (idx - (bi * NTILE - (bi * (bi - 1)) / 2));
    int rowBase = bi * 128;
    int colBase = bj * 128;
    bool diag = (bi == bj);

    int t = threadIdx.x;
    if (t < 128)
        krow[t] = keys[rowBase + t];
    else
        kcol[t - 128] = keys[colBase + (t - 128)];

    int wave = t >> 6, lane = t & 63;
    int wm = wave >> 1, wn = wave & 1;
    int quad = lane >> 4, l16 = lane & 15;

    floatx4 acc[4][4] = {};

    for (int s = 0; s < 4; ++s) {
        __syncthreads();  // previous stage's LDS reads done (also fences keys)
#pragma unroll
        for (int i = 0; i < 4; ++i) {
            int sa = i * 256 + t;             // slot 0..1023
            int c = sa >> 7, row = sa & 127;  // chunk, tile-row
            size_t gOff = (size_t)row * D_DIM + s * 64 + c * 8;
            load_lds16(Zn + (size_t)rowBase * D_DIM + gOff, &As[sa * 8]);
            load_lds16(Zn + (size_t)colBase * D_DIM + gOff, &Bs[sa * 8]);
        }
        __syncthreads();  // staging complete (vmcnt drained before barrier)

#pragma unroll
        for (int k2 = 0; k2 < 2; ++k2) {
            int cb = k2 * 4 + quad;
            short8 afr[4], bfr[4];
#pragma unroll
            for (int mt = 0; mt < 4; ++mt)
                afr[mt] = *(const short8*)&As[(cb * 128 + wm * 64 + mt * 16 + l16) * 8];
#pragma unroll
            for (int nt = 0; nt < 4; ++nt)
                bfr[nt] = *(const short8*)&Bs[(cb * 128 + wn * 64 + nt * 16 + l16) * 8];
#pragma unroll
            for (int mt = 0; mt < 4; ++mt)
#pragma unroll
                for (int nt = 0; nt < 4; ++nt)
                    acc[mt][nt] = __builtin_amdgcn_mfma_f32_16x16x32_bf16(
                        afr[mt], bfr[nt], acc[mt][nt], 0, 0, 0);
        }
    }

    __syncthreads();  // all MFMA fragment reads done; As/Bs reusable

    // per-wave transpose slice buffer (16 rows x 64 cols -> [64][17] fp32),
    // carved out of the dead As/Bs staging LDS (wave-private, no barriers)
    float* Tt = (wave < 2) ? (float*)(As + wave * 2176)
                           : (float*)(Bs + (wave - 2) * 2176);

    // C/D layout: col = lane&15, row = quad*4 + reg  [m89/m91 verified]
#pragma unroll
    for (int mt = 0; mt < 4; ++mt) {
#pragma unroll
        for (int nt = 0; nt < 4; ++nt) {
            int ljL = nt * 16 + l16;  // col within wave quadrant, 0..63
            int gj = colBase + wn * 64 + ljL;
            uint4 kj = kcol[wn * 64 + ljL];
#pragma unroll
            for (int r = 0; r < 4; ++r) {
                int liL = mt * 16 + quad * 4 + r;  // row within wave, 0..63
                int gi = rowBase + wm * 64 + liL;
                float s = acc[mt][nt][r];
                float v = 0.0f;
                if (s >= 0.5f && gi != gj) {
                    uint4 ki = krow[wm * 64 + liL];
                    int c = zbytes(ki.x ^ kj.x) + zbytes(ki.y ^ kj.y) +
                            zbytes(ki.z ^ kj.z) + zbytes(ki.w ^ kj.w);
                    v = s * (float)c;
                }
                out[(size_t)gi * N_PTS + gj] = v;
                Tt[ljL * 17 + (quad * 4 + r)] = v;  // stride 17: conflict-free
            }
        }
        if (!diag) {
            // mirror store of this 16x64 slice, transposed, coalesced
            size_t mBase = (size_t)(colBase + wn * 64) * N_PTS + rowBase +
                           wm * 64 + mt * 16 + l16;
#pragma unroll
            for (int it = 0; it < 16; ++it) {
                int gjL = it * 4 + quad;
                float v = Tt[gjL * 17 + l16];
                out[mBase + (size_t)gjL * N_PTS] = v;
            }
        }
    }
}

extern "C" void kernel_launch(void* const* d_in, const int* in_sizes, int n_in,
                              void* d_out, int out_size, void* d_ws,
                              size_t ws_size, hipStream_t stream) {
    const float* Z = (const float*)d_in[0];       // (8192, 256) fp32
    const float* planes = (const float*)d_in[1];  // (128, 256) fp32
    float* out = (float*)d_out;                   // (8192, 8192) fp32

    unsigned short* Zn = (unsigned short*)d_ws;  // 8192*256 bf16 = 4 MB
    unsigned int* keys4 =
        (unsigned int*)((char*)d_ws + (size_t)N_PTS * D_DIM * 2);  // 128 KB

    norm_kernel<<<N_PTS, 64, 0, stream>>>(Z, Zn);
    keys_kernel<<<N_PTS / 32, 256, 0, stream>>>(Z, planes, keys4);
    int nblocks = NTILE * (NTILE + 1) / 2;  // 2080 upper-tri 128x128 tiles
    gemm_kernel<<<nblocks, 256, 0, stream>>>(Zn, (const uint4*)keys4, out);
}

// Round 5
// 333.086 us; speedup vs baseline: 1.0411x; 1.0411x over previous
//
#include <hip/hip_runtime.h>

typedef __attribute__((ext_vector_type(8))) short short8;   // 8 bf16 = 4 VGPRs
typedef __attribute__((ext_vector_type(4))) float floatx4;  // MFMA acc / NT store

#define N_PTS 8192
#define D_DIM 256
#define N_PLANES 128

// round-to-nearest-even float -> bf16 bits
__device__ inline unsigned short f2bf(float f) {
    unsigned int x = __float_as_uint(f);
    unsigned int r = (x + 0x7fffu + ((x >> 16) & 1u)) >> 16;
    return (unsigned short)r;
}

// count of zero bytes in w (exact per-byte SWAR, no cross-byte carry)
__device__ inline int zbytes(unsigned int w) {
    unsigned int t = ((w & 0x7f7f7f7fu) + 0x7f7f7f7fu) | w | 0x7f7f7f7fu;
    return __popc(~t);  // ~t has only bit7 per byte set, iff byte == 0
}

// async global->LDS, 16B per lane; LDS dest must be base + lane*16 (m104/m108)
__device__ inline void load_lds16(const unsigned short* g, unsigned short* l) {
    __builtin_amdgcn_global_load_lds(
        (const __attribute__((address_space(1))) unsigned int*)g,
        (__attribute__((address_space(3))) unsigned int*)l, 16, 0, 0);
}

// ---------------------------------------------------------------------------
// Kernel 1: row-normalize Z (fp32) -> Zn (bf16). One wave per row.
// ---------------------------------------------------------------------------
__global__ void norm_kernel(const float* __restrict__ Z,
                            unsigned short* __restrict__ Zn) {
    int n = blockIdx.x;
    int lane = threadIdx.x;  // 0..63
    const float4* zr = (const float4*)(Z + (size_t)n * D_DIM);
    float4 v = zr[lane];  // 64 lanes x 4 floats = 256
    float ss = v.x * v.x + v.y * v.y + v.z * v.z + v.w * v.w;
#pragma unroll
    for (int off = 32; off > 0; off >>= 1) ss += __shfl_down(ss, off);
    ss = __shfl(ss, 0);
    float inv = rsqrtf(ss);
    ushort4 o;
    o.x = f2bf(v.x * inv);
    o.y = f2bf(v.y * inv);
    o.z = f2bf(v.z * inv);
    o.w = f2bf(v.w * inv);
    ((ushort4*)(Zn + (size_t)n * D_DIM))[lane] = o;
}

// ---------------------------------------------------------------------------
// Kernel 2: LSH keys. Block = 256 threads = 128 planes x 2 point-halves,
// 32 points per block. Points staged in LDS (broadcast reads); each thread
// reads its plane row ONCE (16B/step, register-cached across its 16 points).
// keys4[n][w]: word w = ballot bits of planes 32w..32w+31; byte b of the
// 16-byte key equals the reference band-b signature (same 2^r weighting).
// ---------------------------------------------------------------------------
__global__ __launch_bounds__(256) void keys_kernel(
    const float* __restrict__ Z, const float* __restrict__ planes,
    unsigned int* __restrict__ keys4) {
    __shared__ __align__(16) float zs[32][D_DIM];  // 32 KB
    int t = threadIdx.x;
    int base = blockIdx.x * 32;

    const float4* zsrc = (const float4*)(Z + (size_t)base * D_DIM);
    float4* zdst = (float4*)&zs[0][0];
#pragma unroll
    for (int i = 0; i < 8; ++i) zdst[t + i * 256] = zsrc[t + i * 256];
    __syncthreads();

    int p = t & 127;   // plane index
    int hf = t >> 7;   // 0/1 -> points 0..15 / 16..31
    int wave = t >> 6, lane = t & 63;
    const float4* pr = (const float4*)(planes + (size_t)p * D_DIM);

    float acc[16] = {};
    for (int kk = 0; kk < D_DIM / 4; ++kk) {
        float4 pv = pr[kk];
#pragma unroll
        for (int j = 0; j < 16; ++j) {
            float4 zv = *(const float4*)&zs[hf * 16 + j][kk * 4];
            acc[j] += pv.x * zv.x + pv.y * zv.y + pv.z * zv.z + pv.w * zv.w;
        }
    }

#pragma unroll
    for (int j = 0; j < 16; ++j) {
        unsigned long long mask = __ballot(acc[j] >= 0.0f);
        if (lane < 2) {
            keys4[(size_t)(base + hf * 16 + j) * 4 + (wave & 1) * 2 + lane] =
                (unsigned int)(mask >> (32 * lane));
        }
    }
}

// ---------------------------------------------------------------------------
// Kernel 3: sim GEMM (bf16 MFMA) + LSH-count epilogue. Full 64x64 grid.
// 128x128 tile / block, 4 waves (2x2), each wave 64x64 via 4x4 MFMA tiles.
// K staged in 4 chunks of BK=64 via global_load_lds (16B), chunk-major LDS.
// Epilogue: thresholded values routed through a wave-private LDS transpose
// so stores are floatx4 (16 lanes x 16B = 256B full-line segments), with
// nontemporal hint (out is write-once, never re-read).
// ---------------------------------------------------------------------------
__global__ __launch_bounds__(256) void gemm_kernel(
    const unsigned short* __restrict__ Zn, const uint4* __restrict__ keys,
    float* __restrict__ out) {
    __shared__ __align__(16) unsigned short stage[2048 * 8];  // 32 KB: As|Bs
    __shared__ uint4 krow[128];
    __shared__ uint4 kcol[128];
    unsigned short* As = stage;         // 8 chunks x 128 rows x 16B
    unsigned short* Bs = stage + 8192;  // same, for B tile

    int t = threadIdx.x;
    int rowBase = blockIdx.y * 128;
    int colBase = blockIdx.x * 128;
    if (t < 128)
        krow[t] = keys[rowBase + t];
    else
        kcol[t - 128] = keys[colBase + (t - 128)];

    int wave = t >> 6, lane = t & 63;
    int wm = wave >> 1, wn = wave & 1;
    int quad = lane >> 4, l16 = lane & 15;

    floatx4 acc[4][4] = {};

    for (int s = 0; s < 4; ++s) {
        __syncthreads();  // prev stage's LDS reads done (also fences keys)
#pragma unroll
        for (int i = 0; i < 4; ++i) {
            int sa = i * 256 + t;             // slot 0..1023
            int c = sa >> 7, row = sa & 127;  // chunk, tile-row
            size_t gOff = (size_t)row * D_DIM + s * 64 + c * 8;
            load_lds16(Zn + (size_t)rowBase * D_DIM + gOff, &As[sa * 8]);
            load_lds16(Zn + (size_t)colBase * D_DIM + gOff, &Bs[sa * 8]);
        }
        __syncthreads();  // staging complete

#pragma unroll
        for (int k2 = 0; k2 < 2; ++k2) {
            int cb = k2 * 4 + quad;
            short8 afr[4], bfr[4];
#pragma unroll
            for (int mt = 0; mt < 4; ++mt)
                afr[mt] = *(const short8*)&As[(cb * 128 + wm * 64 + mt * 16 + l16) * 8];
#pragma unroll
            for (int nt = 0; nt < 4; ++nt)
                bfr[nt] = *(const short8*)&Bs[(cb * 128 + wn * 64 + nt * 16 + l16) * 8];
#pragma unroll
            for (int mt = 0; mt < 4; ++mt)
#pragma unroll
                for (int nt = 0; nt < 4; ++nt)
                    acc[mt][nt] = __builtin_amdgcn_mfma_f32_16x16x32_bf16(
                        afr[mt], bfr[nt], acc[mt][nt], 0, 0, 0);
        }
    }

    __syncthreads();  // all MFMA fragment reads done; stage[] reusable

    // wave-private transpose buffer: 16 rows x 68-word stride (fp32)
    // 4 waves x 4352B = 17408B, inside the dead 32KB stage[]
    float* T = (float*)stage + wave * 1088;

    // C/D layout: col = lane&15, row = quad*4 + reg  [m89/m91 verified]
#pragma unroll
    for (int mt = 0; mt < 4; ++mt) {
#pragma unroll
        for (int nt = 0; nt < 4; ++nt) {
            int lj = nt * 16 + l16;  // col within wave quadrant, 0..63
            int gj = colBase + wn * 64 + lj;
            uint4 kj = kcol[wn * 64 + lj];
#pragma unroll
            for (int r = 0; r < 4; ++r) {
                int row16 = quad * 4 + r;  // row within mt slice, 0..15
                int gi = rowBase + wm * 64 + mt * 16 + row16;
                float s = acc[mt][nt][r];
                float v = 0.0f;
                if (s >= 0.5f && gi != gj) {
                    uint4 ki = krow[wm * 64 + mt * 16 + row16];
                    int c = zbytes(ki.x ^ kj.x) + zbytes(ki.y ^ kj.y) +
                            zbytes(ki.z ^ kj.z) + zbytes(ki.w ^ kj.w);
                    v = s * (float)c;
                }
                T[row16 * 68 + lj] = v;  // 2-way bank alias: free
            }
        }
        // floatx4 stores: rows it*4+quad, 16 lanes x 16B = 256B/row contiguous
#pragma unroll
        for (int it = 0; it < 4; ++it) {
            int row16 = it * 4 + quad;
            floatx4 v4 = *(const floatx4*)&T[row16 * 68 + 4 * l16];
            size_t o = (size_t)(rowBase + wm * 64 + mt * 16 + row16) * N_PTS +
                       colBase + wn * 64 + 4 * l16;
            __builtin_nontemporal_store(v4, (floatx4*)(out + o));
        }
    }
}

extern "C" void kernel_launch(void* const* d_in, const int* in_sizes, int n_in,
                              void* d_out, int out_size, void* d_ws,
                              size_t ws_size, hipStream_t stream) {
    const float* Z = (const float*)d_in[0];       // (8192, 256) fp32
    const float* planes = (const float*)d_in[1];  // (128, 256) fp32
    float* out = (float*)d_out;                   // (8192, 8192) fp32

    unsigned short* Zn = (unsigned short*)d_ws;  // 8192*256 bf16 = 4 MB
    unsigned int* keys4 =
        (unsigned int*)((char*)d_ws + (size_t)N_PTS * D_DIM * 2);  // 128 KB

    norm_kernel<<<N_PTS, 64, 0, stream>>>(Z, Zn);
    keys_kernel<<<N_PTS / 32, 256, 0, stream>>>(Z, planes, keys4);
    gemm_kernel<<<dim3(N_PTS / 128, N_PTS / 128), 256, 0, stream>>>(
        Zn, (const uint4*)keys4, out);
}

// Round 6
// 328.436 us; speedup vs baseline: 1.0558x; 1.0142x over previous
//
#include <hip/hip_runtime.h>

typedef __attribute__((ext_vector_type(8))) short short8;   // 8 bf16 = 4 VGPRs
typedef __attribute__((ext_vector_type(4))) float floatx4;  // MFMA acc / NT store

#define N_PTS 8192
#define D_DIM 256
#define N_PLANES 128

// round-to-nearest-even float -> bf16 bits
__device__ inline unsigned short f2bf(float f) {
    unsigned int x = __float_as_uint(f);
    unsigned int r = (x + 0x7fffu + ((x >> 16) & 1u)) >> 16;
    return (unsigned short)r;
}

// count of zero bytes in w (exact per-byte SWAR, no cross-byte carry)
__device__ inline int zbytes(unsigned int w) {
    unsigned int t = ((w & 0x7f7f7f7fu) + 0x7f7f7f7fu) | w | 0x7f7f7f7fu;
    return __popc(~t);  // ~t has only bit7 per byte set, iff byte == 0
}

// async global->LDS, 16B per lane; LDS dest must be base + lane*16 (m104/m108)
__device__ inline void load_lds16(const unsigned short* g, unsigned short* l) {
    __builtin_amdgcn_global_load_lds(
        (const __attribute__((address_space(1))) unsigned int*)g,
        (__attribute__((address_space(3))) unsigned int*)l, 16, 0, 0);
}

// ---------------------------------------------------------------------------
// Kernel 1: row-normalize Z (fp32) -> Zn (bf16). One wave per row.
// ---------------------------------------------------------------------------
__global__ void norm_kernel(const float* __restrict__ Z,
                            unsigned short* __restrict__ Zn) {
    int n = blockIdx.x;
    int lane = threadIdx.x;  // 0..63
    const float4* zr = (const float4*)(Z + (size_t)n * D_DIM);
    float4 v = zr[lane];  // 64 lanes x 4 floats = 256
    float ss = v.x * v.x + v.y * v.y + v.z * v.z + v.w * v.w;
#pragma unroll
    for (int off = 32; off > 0; off >>= 1) ss += __shfl_down(ss, off);
    ss = __shfl(ss, 0);
    float inv = rsqrtf(ss);
    ushort4 o;
    o.x = f2bf(v.x * inv);
    o.y = f2bf(v.y * inv);
    o.z = f2bf(v.z * inv);
    o.w = f2bf(v.w * inv);
    ((ushort4*)(Zn + (size_t)n * D_DIM))[lane] = o;
}

// ---------------------------------------------------------------------------
// Kernel 2: LSH keys. Block = 256 threads = 128 planes x 2 point-halves,
// 16 points per block (512 blocks -> 2 blocks/CU for latency hiding).
// Points staged in LDS (wave-uniform broadcast reads); each thread reads its
// plane row once per kk (16B, L1-resident), register-carried across 8 points.
// keys4[n][w]: word w = ballot bits of planes 32w..32w+31; byte b of the
// 16-byte key equals the reference band-b signature (same 2^r weighting).
// ---------------------------------------------------------------------------
__global__ __launch_bounds__(256) void keys_kernel(
    const float* __restrict__ Z, const float* __restrict__ planes,
    unsigned int* __restrict__ keys4) {
    __shared__ __align__(16) float zs[16][D_DIM];  // 16 KB
    int t = threadIdx.x;
    int base = blockIdx.x * 16;

    const float4* zsrc = (const float4*)(Z + (size_t)base * D_DIM);
    float4* zdst = (float4*)&zs[0][0];
#pragma unroll
    for (int i = 0; i < 4; ++i) zdst[t + i * 256] = zsrc[t + i * 256];
    __syncthreads();

    int p = t & 127;   // plane index
    int hf = t >> 7;   // 0/1 -> points 0..7 / 8..15
    int wave = t >> 6, lane = t & 63;
    const float4* pr = (const float4*)(planes + (size_t)p * D_DIM);

    float acc[8] = {};
    for (int kk = 0; kk < D_DIM / 4; ++kk) {
        float4 pv = pr[kk];
#pragma unroll
        for (int j = 0; j < 8; ++j) {
            float4 zv = *(const float4*)&zs[hf * 8 + j][kk * 4];
            acc[j] += pv.x * zv.x + pv.y * zv.y + pv.z * zv.z + pv.w * zv.w;
        }
    }

#pragma unroll
    for (int j = 0; j < 8; ++j) {
        unsigned long long mask = __ballot(acc[j] >= 0.0f);
        if (lane < 2) {
            keys4[(size_t)(base + hf * 8 + j) * 4 + (wave & 1) * 2 + lane] =
                (unsigned int)(mask >> (32 * lane));
        }
    }
}

// ---------------------------------------------------------------------------
// Kernel 3: sim GEMM (bf16 MFMA) + sparse LSH epilogue. Full 64x64 grid.
// Each block NT-stores its 128x128 zero tile FIRST (overlaps all compute;
// drained by the first K-loop barrier, so later conditional overwrites are
// ordered: release-at-barrier). K staged in 4 chunks of BK=64 via
// global_load_lds (16B), chunk-major LDS. Epilogue computes v and stores
// only nonzero survivors (exec-masked, rare by construction of LSH).
// ---------------------------------------------------------------------------
__global__ __launch_bounds__(256, 3) void gemm_kernel(
    const unsigned short* __restrict__ Zn, const uint4* __restrict__ keys,
    float* __restrict__ out) {
    __shared__ __align__(16) unsigned short stage[2048 * 8];  // 32 KB: As|Bs
    __shared__ uint4 krow[128];
    __shared__ uint4 kcol[128];
    unsigned short* As = stage;         // 8 chunks x 128 rows x 16B
    unsigned short* Bs = stage + 8192;  // same, for B tile

    int t = threadIdx.x;
    int rowBase = blockIdx.y * 128;
    int colBase = blockIdx.x * 128;
    if (t < 128)
        krow[t] = keys[rowBase + t];
    else
        kcol[t - 128] = keys[colBase + (t - 128)];

    // zero-fill this block's output tile up-front: 16 floatx4/thread,
    // per-wave 2 rows x 512B contiguous segments, NT (write-once stream)
    {
        float* tileOut = out + (size_t)rowBase * N_PTS + colBase;
        floatx4 z4 = {0.f, 0.f, 0.f, 0.f};
#pragma unroll
        for (int i = 0; i < 16; ++i) {
            int slot = i * 256 + t;  // 0..4095
            int row = slot >> 5;     // 0..127
            int c4 = slot & 31;      // 0..31 (float4 column)
            __builtin_nontemporal_store(
                z4, (floatx4*)(tileOut + (size_t)row * N_PTS + c4 * 4));
        }
    }

    int wave = t >> 6, lane = t & 63;
    int wm = wave >> 1, wn = wave & 1;
    int quad = lane >> 4, l16 = lane & 15;

    floatx4 acc[4][4] = {};

    for (int s = 0; s < 4; ++s) {
        __syncthreads();  // drains zero-stores (s=0) / prev-stage LDS reads
#pragma unroll
        for (int i = 0; i < 4; ++i) {
            int sa = i * 256 + t;             // slot 0..1023
            int c = sa >> 7, row = sa & 127;  // chunk, tile-row
            size_t gOff = (size_t)row * D_DIM + s * 64 + c * 8;
            load_lds16(Zn + (size_t)rowBase * D_DIM + gOff, &As[sa * 8]);
            load_lds16(Zn + (size_t)colBase * D_DIM + gOff, &Bs[sa * 8]);
        }
        __syncthreads();  // staging complete

#pragma unroll
        for (int k2 = 0; k2 < 2; ++k2) {
            int cb = k2 * 4 + quad;
            short8 afr[4], bfr[4];
#pragma unroll
            for (int mt = 0; mt < 4; ++mt)
                afr[mt] = *(const short8*)&As[(cb * 128 + wm * 64 + mt * 16 + l16) * 8];
#pragma unroll
            for (int nt = 0; nt < 4; ++nt)
                bfr[nt] = *(const short8*)&Bs[(cb * 128 + wn * 64 + nt * 16 + l16) * 8];
#pragma unroll
            for (int mt = 0; mt < 4; ++mt)
#pragma unroll
                for (int nt = 0; nt < 4; ++nt)
                    acc[mt][nt] = __builtin_amdgcn_mfma_f32_16x16x32_bf16(
                        afr[mt], bfr[nt], acc[mt][nt], 0, 0, 0);
        }
    }

    // Sparse epilogue. C/D layout: col = lane&15, row = quad*4 + reg
    // [m89/m91 verified]. Store only survivors (threshold+off-diag).
#pragma unroll
    for (int mt = 0; mt < 4; ++mt) {
#pragma unroll
        for (int nt = 0; nt < 4; ++nt) {
            int lj = nt * 16 + l16;  // col within wave quadrant, 0..63
            int gj = colBase + wn * 64 + lj;
            uint4 kj = kcol[wn * 64 + lj];
#pragma unroll
            for (int r = 0; r < 4; ++r) {
                int liL = wm * 64 + mt * 16 + quad * 4 + r;
                int gi = rowBase + liL;
                float s = acc[mt][nt][r];
                if (s >= 0.5f && gi != gj) {
                    uint4 ki = krow[liL];
                    int c = zbytes(ki.x ^ kj.x) + zbytes(ki.y ^ kj.y) +
                            zbytes(ki.z ^ kj.z) + zbytes(ki.w ^ kj.w);
                    out[(size_t)gi * N_PTS + gj] = s * (float)c;
                }
            }
        }
    }
}

extern "C" void kernel_launch(void* const* d_in, const int* in_sizes, int n_in,
                              void* d_out, int out_size, void* d_ws,
                              size_t ws_size, hipStream_t stream) {
    const float* Z = (const float*)d_in[0];       // (8192, 256) fp32
    const float* planes = (const float*)d_in[1];  // (128, 256) fp32
    float* out = (float*)d_out;                   // (8192, 8192) fp32

    unsigned short* Zn = (unsigned short*)d_ws;  // 8192*256 bf16 = 4 MB
    unsigned int* keys4 =
        (unsigned int*)((char*)d_ws + (size_t)N_PTS * D_DIM * 2);  // 128 KB

    norm_kernel<<<N_PTS, 64, 0, stream>>>(Z, Zn);
    keys_kernel<<<N_PTS / 16, 256, 0, stream>>>(Z, planes, keys4);
    gemm_kernel<<<dim3(N_PTS / 128, N_PTS / 128), 256, 0, stream>>>(
        Zn, (const uint4*)keys4, out);
}